// Round 1
// baseline (356.340 us; speedup 1.0000x reference)
//
#include <hip/hip_runtime.h>

#define NTOK 8192
#define DDIM 1024
#define HDIM 2048
#define ODIM 1024
#define NEXP 8
#define OUTW (ODIM + NEXP)   // 1032

typedef __bf16 bf16_t;
typedef bf16_t bf16x8 __attribute__((ext_vector_type(8)));
typedef bf16_t bf16x4 __attribute__((ext_vector_type(4)));
typedef float f32x4 __attribute__((ext_vector_type(4)));

__device__ __forceinline__ void gld_lds16(bf16_t* lds, const bf16_t* g) {
  __builtin_amdgcn_global_load_lds(
      (__attribute__((address_space(1))) void*)g,
      (__attribute__((address_space(3))) void*)lds, 16, 0, 0);
}

__global__ void zero_cnt_kernel(int* cnt) {
  if (threadIdx.x < NEXP) cnt[threadIdx.x] = 0;
}

__global__ void route_kernel(const int* __restrict__ idx, float* __restrict__ out,
                             int* __restrict__ rank, int* cnt) {
  int n = blockIdx.x * 256 + threadIdx.x;
  int e = idx[n];
  rank[n] = atomicAdd(&cnt[e], 1);
  float* o = out + (size_t)n * OUTW + ODIM;
#pragma unroll
  for (int j = 0; j < NEXP; j++) o[j] = (j == e) ? 1.0f : 0.0f;
}

__global__ void scan_kernel(const int* __restrict__ cnt, int* __restrict__ off) {
  if (threadIdx.x == 0) {
    int s = 0;
    for (int e = 0; e < NEXP; e++) { off[e] = s; s += cnt[e]; }
  }
}

__global__ void gather_kernel(const float* __restrict__ x, const int* __restrict__ idx,
                              const int* __restrict__ rank, const int* __restrict__ off,
                              bf16_t* __restrict__ xg, int* __restrict__ tok_of_pos) {
  int n = blockIdx.x;
  int e = idx[n];
  int pos = off[e] + rank[n];
  if (threadIdx.x == 0) tok_of_pos[pos] = n;
  float4 v = ((const float4*)(x + (size_t)n * DDIM))[threadIdx.x];
  bf16x4 o;
  o[0] = (bf16_t)v.x; o[1] = (bf16_t)v.y; o[2] = (bf16_t)v.z; o[3] = (bf16_t)v.w;
  *(bf16x4*)(xg + (size_t)pos * DDIM + threadIdx.x * 4) = o;
}

// transpose+convert: src [E][R][C] f32 -> dst [E][C][R] bf16
__global__ void wtrans_kernel(const float* __restrict__ src, bf16_t* __restrict__ dst,
                              int R, int C) {
  __shared__ float t[64][65];
  int e = blockIdx.z;
  int c0 = blockIdx.x * 64, r0 = blockIdx.y * 64;
  int tx = threadIdx.x & 15, ty = threadIdx.x >> 4;
  const float* s = src + (size_t)e * R * C;
#pragma unroll
  for (int i = 0; i < 4; i++) {
    float4 v = *(const float4*)&s[(size_t)(r0 + ty + i * 16) * C + c0 + tx * 4];
    t[ty + i * 16][tx * 4 + 0] = v.x;
    t[ty + i * 16][tx * 4 + 1] = v.y;
    t[ty + i * 16][tx * 4 + 2] = v.z;
    t[ty + i * 16][tx * 4 + 3] = v.w;
  }
  __syncthreads();
  bf16_t* d = dst + (size_t)e * R * C;
#pragma unroll
  for (int i = 0; i < 4; i++) {
    bf16x4 o;
#pragma unroll
    for (int j = 0; j < 4; j++) o[j] = (bf16_t)t[tx * 4 + j][ty + i * 16];
    *(bf16x4*)&d[(size_t)(c0 + ty + i * 16) * R + r0 + tx * 4] = o;
  }
}

// C[pos][n] = sum_k A[pos][k] * Bt[e][n][k] + bias[e][n]
// rows pos in [off[e], off[e]+cnt[e]) ; A row-major [*, KDIM] bf16, Bt [E][NCOLS][KDIM] bf16
template <int KDIM, int NCOLS, bool TO_BF16>
__global__ __launch_bounds__(256) void gemm_kernel(
    const bf16_t* __restrict__ A, const bf16_t* __restrict__ Bt,
    const float* __restrict__ bias,
    const int* __restrict__ cnt, const int* __restrict__ off,
    const int* __restrict__ tok_of_pos,
    bf16_t* __restrict__ outb, float* __restrict__ outf) {
  const int e = blockIdx.z;
  const int mt = blockIdx.y;
  const int nt = blockIdx.x;
  const int count = cnt[e];
  if (mt * 128 >= count) return;
  const int base = off[e];

  __shared__ bf16_t lA[128 * 32];
  __shared__ bf16_t lB[128 * 32];

  const int tid = threadIdx.x;
  const int lane = tid & 63;
  const int wave = tid >> 6;
  const int mrow = lane & 15;
  const int q = lane >> 4;
  const int wm = (wave & 1) * 64;
  const int wn = (wave >> 1) * 64;

  // staging: chunk c = wave*2+s covers tile rows c*16..c*16+15 ; lane -> (row c*16 + l>>2, k (l&3)*8)
  const bf16_t* pA[2];
  const bf16_t* pB[2];
#pragma unroll
  for (int s = 0; s < 2; s++) {
    int lrow = wave * 32 + s * 16 + (lane >> 2);
    int gr = base + mt * 128 + lrow;
    if (gr > NTOK - 1) gr = NTOK - 1;  // clamp: garbage rows masked at store
    pA[s] = A + (size_t)gr * KDIM + (lane & 3) * 8;
    int nrow = nt * 128 + lrow;
    pB[s] = Bt + ((size_t)e * NCOLS + nrow) * KDIM + (lane & 3) * 8;
  }

  f32x4 acc[4][4] = {};
  const bf16_t* la0 = &lA[(wm + mrow) * 32 + q * 8];
  const bf16_t* lb0 = &lB[(wn + mrow) * 32 + q * 8];

  for (int kk = 0; kk < KDIM; kk += 32) {
#pragma unroll
    for (int s = 0; s < 2; s++) {
      gld_lds16(&lA[(wave * 2 + s) * 512], pA[s] + kk);
      gld_lds16(&lB[(wave * 2 + s) * 512], pB[s] + kk);
    }
    __syncthreads();
    bf16x8 af[4], bfr[4];
#pragma unroll
    for (int i = 0; i < 4; i++) {
      af[i]  = *(const bf16x8*)(la0 + i * 16 * 32);
      bfr[i] = *(const bf16x8*)(lb0 + i * 16 * 32);
    }
#pragma unroll
    for (int i = 0; i < 4; i++)
#pragma unroll
      for (int j = 0; j < 4; j++)
        acc[i][j] = __builtin_amdgcn_mfma_f32_16x16x32_bf16(af[i], bfr[j], acc[i][j], 0, 0, 0);
    __syncthreads();
  }

  const int mlimit = count - mt * 128;
  float bs[4];
#pragma unroll
  for (int j = 0; j < 4; j++)
    bs[j] = bias[(size_t)e * NCOLS + nt * 128 + wn + j * 16 + mrow];

#pragma unroll
  for (int i = 0; i < 4; i++) {
#pragma unroll
    for (int r = 0; r < 4; r++) {
      int ml = wm + i * 16 + q * 4 + r;
      if (ml < mlimit) {
        int prow = base + mt * 128 + ml;
        if constexpr (TO_BF16) {
          bf16_t* orow = outb + (size_t)prow * NCOLS;
#pragma unroll
          for (int j = 0; j < 4; j++)
            orow[nt * 128 + wn + j * 16 + mrow] = (bf16_t)(acc[i][j][r] + bs[j]);
        } else {
          int tok = tok_of_pos[prow];
          float* orow = outf + (size_t)tok * OUTW;
#pragma unroll
          for (int j = 0; j < 4; j++)
            orow[nt * 128 + wn + j * 16 + mrow] = acc[i][j][r] + bs[j];
        }
      }
    }
  }
}

extern "C" void kernel_launch(void* const* d_in, const int* in_sizes, int n_in,
                              void* d_out, int out_size, void* d_ws, size_t ws_size,
                              hipStream_t stream) {
  const float* x  = (const float*)d_in[0];
  const float* W1 = (const float*)d_in[1];
  const float* b1 = (const float*)d_in[2];
  const float* W2 = (const float*)d_in[3];
  const float* b2 = (const float*)d_in[4];
  const int* idx  = (const int*)d_in[5];
  float* out = (float*)d_out;

  char* ws = (char*)d_ws;
  bf16_t* xg  = (bf16_t*)(ws);                 // 16 MB  [N][D] bf16
  bf16_t* hg  = (bf16_t*)(ws + 16777216);      // 32 MB  [N][H] bf16
  bf16_t* Wt1 = (bf16_t*)(ws + 50331648);      // 32 MB  [E][H][D] bf16
  bf16_t* Wt2 = (bf16_t*)(ws + 83886080);      // 32 MB  [E][O][H] bf16
  int* tok    = (int*)(ws + 117440512);        // 32 KB
  int* rank   = (int*)(ws + 117473280);        // 32 KB
  int* cnt    = (int*)(ws + 117506048);
  int* off    = (int*)(ws + 117506080);

  zero_cnt_kernel<<<1, 64, 0, stream>>>(cnt);
  route_kernel<<<NTOK / 256, 256, 0, stream>>>(idx, out, rank, cnt);
  scan_kernel<<<1, 64, 0, stream>>>(cnt, off);
  gather_kernel<<<NTOK, 256, 0, stream>>>(x, idx, rank, off, xg, tok);
  wtrans_kernel<<<dim3(HDIM / 64, DDIM / 64, NEXP), 256, 0, stream>>>(W1, Wt1, DDIM, HDIM);
  wtrans_kernel<<<dim3(ODIM / 64, HDIM / 64, NEXP), 256, 0, stream>>>(W2, Wt2, HDIM, ODIM);
  gemm_kernel<DDIM, HDIM, true><<<dim3(HDIM / 128, NTOK / 128, NEXP), 256, 0, stream>>>(
      xg, Wt1, b1, cnt, off, tok, hg, nullptr);
  gemm_kernel<HDIM, ODIM, false><<<dim3(ODIM / 128, NTOK / 128, NEXP), 256, 0, stream>>>(
      hg, Wt2, b2, cnt, off, tok, nullptr, out);
}

// Round 2
// 314.614 us; speedup vs baseline: 1.1326x; 1.1326x over previous
//
#include <hip/hip_runtime.h>

#define NTOK 8192
#define DDIM 1024
#define HDIM 2048
#define ODIM 1024
#define NEXP 8
#define OUTW (ODIM + NEXP)   // 1032
#define MT_MAX 64            // worst-case m-tiles per expert (all tokens -> one expert)

typedef __bf16 bf16_t;
typedef bf16_t bf16x8 __attribute__((ext_vector_type(8)));
typedef bf16_t bf16x4 __attribute__((ext_vector_type(4)));
typedef float f32x4 __attribute__((ext_vector_type(4)));

__device__ __forceinline__ void gld_lds16(bf16_t* lds, const bf16_t* g) {
  __builtin_amdgcn_global_load_lds(
      (__attribute__((address_space(1))) void*)g,
      (__attribute__((address_space(3))) void*)lds, 16, 0, 0);
}

__global__ void zero_cnt_kernel(int* cnt) {
  if (threadIdx.x < NEXP) cnt[threadIdx.x] = 0;
}

// Per-block LDS histogram: 256 global atomics total instead of 8192.
__global__ void route_kernel(const int* __restrict__ idx, float* __restrict__ out,
                             int* __restrict__ rank, int* cnt) {
  __shared__ int lcnt[NEXP];
  __shared__ int lbase[NEXP];
  int t = threadIdx.x;
  if (t < NEXP) lcnt[t] = 0;
  __syncthreads();
  int n = blockIdx.x * 256 + t;
  int e = idx[n];
  int lr = atomicAdd(&lcnt[e], 1);
  __syncthreads();
  if (t < NEXP) lbase[t] = atomicAdd(&cnt[t], lcnt[t]);
  __syncthreads();
  rank[n] = lbase[e] + lr;
  float* o = out + (size_t)n * OUTW + ODIM;
#pragma unroll
  for (int j = 0; j < NEXP; j++) o[j] = (j == e) ? 1.0f : 0.0f;
}

__global__ void scan_kernel(const int* __restrict__ cnt, int* __restrict__ off) {
  if (threadIdx.x == 0) {
    int s = 0;
    for (int e = 0; e < NEXP; e++) { off[e] = s; s += cnt[e]; }
  }
}

__global__ void gather_kernel(const float* __restrict__ x, const int* __restrict__ idx,
                              const int* __restrict__ rank, const int* __restrict__ off,
                              bf16_t* __restrict__ xg, int* __restrict__ tok_of_pos) {
  int n = blockIdx.x;
  int e = idx[n];
  int pos = off[e] + rank[n];
  if (threadIdx.x == 0) tok_of_pos[pos] = n;
  float4 v = ((const float4*)(x + (size_t)n * DDIM))[threadIdx.x];
  bf16x4 o;
  o[0] = (bf16_t)v.x; o[1] = (bf16_t)v.y; o[2] = (bf16_t)v.z; o[3] = (bf16_t)v.w;
  *(bf16x4*)(xg + (size_t)pos * DDIM + threadIdx.x * 4) = o;
}

// transpose+convert: src [E][R][C] f32 -> dst [E][C][R] bf16
__global__ void wtrans_kernel(const float* __restrict__ src, bf16_t* __restrict__ dst,
                              int R, int C) {
  __shared__ float t[64][65];
  int e = blockIdx.z;
  int c0 = blockIdx.x * 64, r0 = blockIdx.y * 64;
  int tx = threadIdx.x & 15, ty = threadIdx.x >> 4;
  const float* s = src + (size_t)e * R * C;
#pragma unroll
  for (int i = 0; i < 4; i++) {
    float4 v = *(const float4*)&s[(size_t)(r0 + ty + i * 16) * C + c0 + tx * 4];
    t[ty + i * 16][tx * 4 + 0] = v.x;
    t[ty + i * 16][tx * 4 + 1] = v.y;
    t[ty + i * 16][tx * 4 + 2] = v.z;
    t[ty + i * 16][tx * 4 + 3] = v.w;
  }
  __syncthreads();
  bf16_t* d = dst + (size_t)e * R * C;
#pragma unroll
  for (int i = 0; i < 4; i++) {
    bf16x4 o;
#pragma unroll
    for (int j = 0; j < 4; j++) o[j] = (bf16_t)t[tx * 4 + j][ty + i * 16];
    *(bf16x4*)&d[(size_t)(c0 + ty + i * 16) * R + r0 + tx * 4] = o;
  }
}

// C[pos][n] = sum_k A[pos][k] * Bt[e][n][k] + bias[e][n]
// 1D grid, expert = blockIdx.x & 7  ->  expert pinned to one XCD (id%8 round-robin),
// so concurrent blocks on an XCD share one expert's A/B slices in its private L2.
// Within expert, order: m-group inner (MTG tiles ~2MB of A), nt middle, group outer.
template <int KDIM, int NCOLS, int MTG, bool TO_BF16>
__global__ __launch_bounds__(256) void gemm_kernel(
    const bf16_t* __restrict__ A, const bf16_t* __restrict__ Bt,
    const float* __restrict__ bias,
    const int* __restrict__ cnt, const int* __restrict__ off,
    const int* __restrict__ tok_of_pos,
    bf16_t* __restrict__ outb, float* __restrict__ outf) {
  constexpr int NT = NCOLS / 128;
  const int b = blockIdx.x;
  const int e = b & 7;
  int t = b >> 3;
  const int mtl = t % MTG;
  t /= MTG;
  const int nt = t % NT;
  const int g = t / NT;
  const int mt = g * MTG + mtl;

  const int count = cnt[e];
  if (mt * 128 >= count) return;
  const int base = off[e];

  __shared__ bf16_t lA[128 * 32];
  __shared__ bf16_t lB[128 * 32];

  const int tid = threadIdx.x;
  const int lane = tid & 63;
  const int wave = tid >> 6;
  const int mrow = lane & 15;
  const int q = lane >> 4;
  const int wm = (wave & 1) * 64;
  const int wn = (wave >> 1) * 64;

  // staging: chunk c = wave*2+s covers tile rows c*16..c*16+15 ; lane -> (row c*16 + l>>2, k (l&3)*8)
  const bf16_t* pA[2];
  const bf16_t* pB[2];
#pragma unroll
  for (int s = 0; s < 2; s++) {
    int lrow = wave * 32 + s * 16 + (lane >> 2);
    int gr = base + mt * 128 + lrow;
    if (gr > NTOK - 1) gr = NTOK - 1;  // clamp: garbage rows masked at store
    pA[s] = A + (size_t)gr * KDIM + (lane & 3) * 8;
    int nrow = nt * 128 + lrow;
    pB[s] = Bt + ((size_t)e * NCOLS + nrow) * KDIM + (lane & 3) * 8;
  }

  f32x4 acc[4][4] = {};
  const bf16_t* la0 = &lA[(wm + mrow) * 32 + q * 8];
  const bf16_t* lb0 = &lB[(wn + mrow) * 32 + q * 8];

  for (int kk = 0; kk < KDIM; kk += 32) {
#pragma unroll
    for (int s = 0; s < 2; s++) {
      gld_lds16(&lA[(wave * 2 + s) * 512], pA[s] + kk);
      gld_lds16(&lB[(wave * 2 + s) * 512], pB[s] + kk);
    }
    __syncthreads();
    bf16x8 af[4], bfr[4];
#pragma unroll
    for (int i = 0; i < 4; i++) {
      af[i]  = *(const bf16x8*)(la0 + i * 16 * 32);
      bfr[i] = *(const bf16x8*)(lb0 + i * 16 * 32);
    }
#pragma unroll
    for (int i = 0; i < 4; i++)
#pragma unroll
      for (int j = 0; j < 4; j++)
        acc[i][j] = __builtin_amdgcn_mfma_f32_16x16x32_bf16(af[i], bfr[j], acc[i][j], 0, 0, 0);
    __syncthreads();
  }

  const int mlimit = count - mt * 128;
  float bs[4];
#pragma unroll
  for (int j = 0; j < 4; j++)
    bs[j] = bias[(size_t)e * NCOLS + nt * 128 + wn + j * 16 + mrow];

#pragma unroll
  for (int i = 0; i < 4; i++) {
#pragma unroll
    for (int r = 0; r < 4; r++) {
      int ml = wm + i * 16 + q * 4 + r;
      if (ml < mlimit) {
        int prow = base + mt * 128 + ml;
        if constexpr (TO_BF16) {
          bf16_t* orow = outb + (size_t)prow * NCOLS;
#pragma unroll
          for (int j = 0; j < 4; j++)
            orow[nt * 128 + wn + j * 16 + mrow] = (bf16_t)(acc[i][j][r] + bs[j]);
        } else {
          int tok = tok_of_pos[prow];
          float* orow = outf + (size_t)tok * OUTW;
#pragma unroll
          for (int j = 0; j < 4; j++)
            orow[nt * 128 + wn + j * 16 + mrow] = acc[i][j][r] + bs[j];
        }
      }
    }
  }
}

extern "C" void kernel_launch(void* const* d_in, const int* in_sizes, int n_in,
                              void* d_out, int out_size, void* d_ws, size_t ws_size,
                              hipStream_t stream) {
  const float* x  = (const float*)d_in[0];
  const float* W1 = (const float*)d_in[1];
  const float* b1 = (const float*)d_in[2];
  const float* W2 = (const float*)d_in[3];
  const float* b2 = (const float*)d_in[4];
  const int* idx  = (const int*)d_in[5];
  float* out = (float*)d_out;

  char* ws = (char*)d_ws;
  bf16_t* xg  = (bf16_t*)(ws);                 // 16 MB  [N][D] bf16
  bf16_t* hg  = (bf16_t*)(ws + 16777216);      // 32 MB  [N][H] bf16
  bf16_t* Wt1 = (bf16_t*)(ws + 50331648);      // 32 MB  [E][H][D] bf16
  bf16_t* Wt2 = (bf16_t*)(ws + 83886080);      // 32 MB  [E][O][H] bf16
  int* tok    = (int*)(ws + 117440512);        // 32 KB
  int* rank   = (int*)(ws + 117473280);        // 32 KB
  int* cnt    = (int*)(ws + 117506048);
  int* off    = (int*)(ws + 117506080);

  zero_cnt_kernel<<<1, 64, 0, stream>>>(cnt);
  route_kernel<<<NTOK / 256, 256, 0, stream>>>(idx, out, rank, cnt);
  scan_kernel<<<1, 64, 0, stream>>>(cnt, off);
  gather_kernel<<<NTOK, 256, 0, stream>>>(x, idx, rank, off, xg, tok);
  wtrans_kernel<<<dim3(HDIM / 64, DDIM / 64, NEXP), 256, 0, stream>>>(W1, Wt1, DDIM, HDIM);
  wtrans_kernel<<<dim3(ODIM / 64, HDIM / 64, NEXP), 256, 0, stream>>>(W2, Wt2, HDIM, ODIM);
  // GEMM1: K=1024, NCOLS=2048, MTG=8 (8*128 rows * 1024 k * 2B = 2MB A-group)
  gemm_kernel<DDIM, HDIM, 8, true>
      <<<NEXP * MT_MAX * (HDIM / 128), 256, 0, stream>>>(
      xg, Wt1, b1, cnt, off, tok, hg, nullptr);
  // GEMM2: K=2048, NCOLS=1024, MTG=4 (4*128 rows * 2048 k * 2B = 2MB A-group)
  gemm_kernel<HDIM, ODIM, 4, false>
      <<<NEXP * MT_MAX * (ODIM / 128), 256, 0, stream>>>(
      hg, Wt2, b2, cnt, off, tok, nullptr, out);
}

// Round 3
// 314.528 us; speedup vs baseline: 1.1329x; 1.0003x over previous
//
#include <hip/hip_runtime.h>

#define NTOK 8192
#define DDIM 1024
#define HDIM 2048
#define ODIM 1024
#define NEXP 8
#define OUTW (ODIM + NEXP)   // 1032
#define MT_MAX 64            // worst-case m-tiles per expert (all tokens -> one expert)

typedef __bf16 bf16_t;
typedef bf16_t bf16x8 __attribute__((ext_vector_type(8)));
typedef bf16_t bf16x4 __attribute__((ext_vector_type(4)));
typedef float f32x4 __attribute__((ext_vector_type(4)));

__device__ __forceinline__ void gld_lds16(bf16_t* lds, const bf16_t* g) {
  __builtin_amdgcn_global_load_lds(
      (__attribute__((address_space(1))) void*)g,
      (__attribute__((address_space(3))) void*)lds, 16, 0, 0);
}

__global__ void zero_cnt_kernel(int* cnt) {
  if (threadIdx.x < NEXP) cnt[threadIdx.x] = 0;
}

// Per-block LDS histogram: 256 global atomics total instead of 8192.
__global__ void route_kernel(const int* __restrict__ idx, float* __restrict__ out,
                             int* __restrict__ rank, int* cnt) {
  __shared__ int lcnt[NEXP];
  __shared__ int lbase[NEXP];
  int t = threadIdx.x;
  if (t < NEXP) lcnt[t] = 0;
  __syncthreads();
  int n = blockIdx.x * 256 + t;
  int e = idx[n];
  int lr = atomicAdd(&lcnt[e], 1);
  __syncthreads();
  if (t < NEXP) lbase[t] = atomicAdd(&cnt[t], lcnt[t]);
  __syncthreads();
  rank[n] = lbase[e] + lr;
  float* o = out + (size_t)n * OUTW + ODIM;
#pragma unroll
  for (int j = 0; j < NEXP; j++) o[j] = (j == e) ? 1.0f : 0.0f;
}

__global__ void scan_kernel(const int* __restrict__ cnt, int* __restrict__ off) {
  if (threadIdx.x == 0) {
    int s = 0;
    for (int e = 0; e < NEXP; e++) { off[e] = s; s += cnt[e]; }
  }
}

__global__ void gather_kernel(const float* __restrict__ x, const int* __restrict__ idx,
                              const int* __restrict__ rank, const int* __restrict__ off,
                              bf16_t* __restrict__ xg, int* __restrict__ tok_of_pos) {
  int n = blockIdx.x;
  int e = idx[n];
  int pos = off[e] + rank[n];
  if (threadIdx.x == 0) tok_of_pos[pos] = n;
  float4 v = ((const float4*)(x + (size_t)n * DDIM))[threadIdx.x];
  bf16x4 o;
  o[0] = (bf16_t)v.x; o[1] = (bf16_t)v.y; o[2] = (bf16_t)v.z; o[3] = (bf16_t)v.w;
  *(bf16x4*)(xg + (size_t)pos * DDIM + threadIdx.x * 4) = o;
}

// transpose+convert: src [E][R][C] f32 -> dst [E][C][R] bf16
// tile 128(r) x 64(c); 256B-segment reads, 16B/lane bf16x8 writes (128B segments);
// LDS stride 65 words -> all LDS patterns 2-way (free).
__global__ __launch_bounds__(256) void wtrans_kernel(const float* __restrict__ src,
                                                     bf16_t* __restrict__ dst,
                                                     int R, int C) {
  __shared__ float t[128][65];
  int e = blockIdx.z;
  int c0 = blockIdx.x * 64, r0g = blockIdx.y * 128;
  int tid = threadIdx.x;
  const float* s = src + (size_t)e * R * C;
#pragma unroll
  for (int p = 0; p < 8; p++) {
    int r = (tid >> 4) + p * 16;
    int c4 = (tid & 15) * 4;
    float4 v = *(const float4*)&s[(size_t)(r0g + r) * C + c0 + c4];
    t[r][c4 + 0] = v.x;
    t[r][c4 + 1] = v.y;
    t[r][c4 + 2] = v.z;
    t[r][c4 + 3] = v.w;
  }
  __syncthreads();
  bf16_t* d = dst + (size_t)e * R * C;
  int w = tid >> 6, l = tid & 63;
#pragma unroll
  for (int itc = 0; itc < 2; itc++) {
#pragma unroll
    for (int it2 = 0; it2 < 2; it2++) {
      int c = (l >> 3) + 8 * w + 32 * itc;
      int r0 = (l & 7) * 8 + 64 * it2;
      bf16x8 o;
#pragma unroll
      for (int j = 0; j < 8; j++) o[j] = (bf16_t)t[r0 + j][c];
      *(bf16x8*)&d[(size_t)(c0 + c) * R + r0g + r0] = o;
    }
  }
}

// C[pos][n] = sum_k A[pos][k] * Bt[e][n][k] + bias[e][n]
// 1D grid, expert = blockIdx.x & 7  ->  expert pinned to one XCD (id%8 round-robin).
// XOR swizzle: staging lane loads global k-quarter (lane&3)^(row&3) so LDS slot
// (row, qs) holds global quarter qs^(row&3); fragment reads use slot q^(mrow&3).
// -> ds_read_b128 hits all 32 banks (8 lanes/bank-quad), conflict-free.
template <int KDIM, int NCOLS, int MTG, bool TO_BF16>
__global__ __launch_bounds__(256) void gemm_kernel(
    const bf16_t* __restrict__ A, const bf16_t* __restrict__ Bt,
    const float* __restrict__ bias,
    const int* __restrict__ cnt, const int* __restrict__ off,
    const int* __restrict__ tok_of_pos,
    bf16_t* __restrict__ outb, float* __restrict__ outf) {
  constexpr int NT = NCOLS / 128;
  const int b = blockIdx.x;
  const int e = b & 7;
  int t = b >> 3;
  const int mtl = t % MTG;
  t /= MTG;
  const int nt = t % NT;
  const int g = t / NT;
  const int mt = g * MTG + mtl;

  const int count = cnt[e];
  if (mt * 128 >= count) return;
  const int base = off[e];

  __shared__ bf16_t lA[128 * 32];
  __shared__ bf16_t lB[128 * 32];

  const int tid = threadIdx.x;
  const int lane = tid & 63;
  const int wave = tid >> 6;
  const int mrow = lane & 15;
  const int q = lane >> 4;
  const int wm = (wave & 1) * 64;
  const int wn = (wave >> 1) * 64;

  // staging: chunk c = wave*2+s covers tile rows c*16..c*16+15;
  // lane -> (row c*16 + l>>2, k-quarter (l&3)^(row&3))   [XOR swizzle]
  const bf16_t* pA[2];
  const bf16_t* pB[2];
#pragma unroll
  for (int s = 0; s < 2; s++) {
    int lrow = wave * 32 + s * 16 + (lane >> 2);
    int kq = (lane & 3) ^ (lrow & 3);
    int gr = base + mt * 128 + lrow;
    if (gr > NTOK - 1) gr = NTOK - 1;  // clamp: garbage rows masked at store
    pA[s] = A + (size_t)gr * KDIM + kq * 8;
    int nrow = nt * 128 + lrow;
    pB[s] = Bt + ((size_t)e * NCOLS + nrow) * KDIM + kq * 8;
  }

  f32x4 acc[4][4] = {};
  const bf16_t* la0 = &lA[(wm + mrow) * 32 + ((q ^ (mrow & 3)) * 8)];
  const bf16_t* lb0 = &lB[(wn + mrow) * 32 + ((q ^ (mrow & 3)) * 8)];

  for (int kk = 0; kk < KDIM; kk += 32) {
#pragma unroll
    for (int s = 0; s < 2; s++) {
      gld_lds16(&lA[(wave * 2 + s) * 512], pA[s] + kk);
      gld_lds16(&lB[(wave * 2 + s) * 512], pB[s] + kk);
    }
    __syncthreads();
    bf16x8 af[4], bfr[4];
#pragma unroll
    for (int i = 0; i < 4; i++) {
      af[i]  = *(const bf16x8*)(la0 + i * 16 * 32);
      bfr[i] = *(const bf16x8*)(lb0 + i * 16 * 32);
    }
#pragma unroll
    for (int i = 0; i < 4; i++)
#pragma unroll
      for (int j = 0; j < 4; j++)
        acc[i][j] = __builtin_amdgcn_mfma_f32_16x16x32_bf16(af[i], bfr[j], acc[i][j], 0, 0, 0);
    __syncthreads();
  }

  const int mlimit = count - mt * 128;
  float bs[4];
#pragma unroll
  for (int j = 0; j < 4; j++)
    bs[j] = bias[(size_t)e * NCOLS + nt * 128 + wn + j * 16 + mrow];

#pragma unroll
  for (int i = 0; i < 4; i++) {
#pragma unroll
    for (int r = 0; r < 4; r++) {
      int ml = wm + i * 16 + q * 4 + r;
      if (ml < mlimit) {
        int prow = base + mt * 128 + ml;
        if constexpr (TO_BF16) {
          bf16_t* orow = outb + (size_t)prow * NCOLS;
#pragma unroll
          for (int j = 0; j < 4; j++)
            orow[nt * 128 + wn + j * 16 + mrow] = (bf16_t)(acc[i][j][r] + bs[j]);
        } else {
          int tok = tok_of_pos[prow];
          float* orow = outf + (size_t)tok * OUTW;
#pragma unroll
          for (int j = 0; j < 4; j++)
            orow[nt * 128 + wn + j * 16 + mrow] = acc[i][j][r] + bs[j];
        }
      }
    }
  }
}

extern "C" void kernel_launch(void* const* d_in, const int* in_sizes, int n_in,
                              void* d_out, int out_size, void* d_ws, size_t ws_size,
                              hipStream_t stream) {
  const float* x  = (const float*)d_in[0];
  const float* W1 = (const float*)d_in[1];
  const float* b1 = (const float*)d_in[2];
  const float* W2 = (const float*)d_in[3];
  const float* b2 = (const float*)d_in[4];
  const int* idx  = (const int*)d_in[5];
  float* out = (float*)d_out;

  char* ws = (char*)d_ws;
  bf16_t* xg  = (bf16_t*)(ws);                 // 16 MB  [N][D] bf16
  bf16_t* hg  = (bf16_t*)(ws + 16777216);      // 32 MB  [N][H] bf16
  bf16_t* Wt1 = (bf16_t*)(ws + 50331648);      // 32 MB  [E][H][D] bf16
  bf16_t* Wt2 = (bf16_t*)(ws + 83886080);      // 32 MB  [E][O][H] bf16
  int* tok    = (int*)(ws + 117440512);        // 32 KB
  int* rank   = (int*)(ws + 117473280);        // 32 KB
  int* cnt    = (int*)(ws + 117506048);
  int* off    = (int*)(ws + 117506080);

  zero_cnt_kernel<<<1, 64, 0, stream>>>(cnt);
  route_kernel<<<NTOK / 256, 256, 0, stream>>>(idx, out, rank, cnt);
  scan_kernel<<<1, 64, 0, stream>>>(cnt, off);
  gather_kernel<<<NTOK, 256, 0, stream>>>(x, idx, rank, off, xg, tok);
  // W1: R=D=1024, C=H=2048 ; W2: R=H=2048, C=O=1024
  wtrans_kernel<<<dim3(HDIM / 64, DDIM / 128, NEXP), 256, 0, stream>>>(W1, Wt1, DDIM, HDIM);
  wtrans_kernel<<<dim3(ODIM / 64, HDIM / 128, NEXP), 256, 0, stream>>>(W2, Wt2, HDIM, ODIM);
  // GEMM1: K=1024, NCOLS=2048, MTG=8 (8*128 rows * 1024 k * 2B = 2MB A-group)
  gemm_kernel<DDIM, HDIM, 8, true>
      <<<NEXP * MT_MAX * (HDIM / 128), 256, 0, stream>>>(
      xg, Wt1, b1, cnt, off, tok, hg, nullptr);
  // GEMM2: K=2048, NCOLS=1024, MTG=4 (4*128 rows * 2048 k * 2B = 2MB A-group)
  gemm_kernel<HDIM, ODIM, 4, false>
      <<<NEXP * MT_MAX * (ODIM / 128), 256, 0, stream>>>(
      hg, Wt2, b2, cnt, off, tok, nullptr, out);
}